// Round 4
// baseline (353.782 us; speedup 1.0000x reference)
//
#include <hip/hip_runtime.h>

typedef __attribute__((ext_vector_type(8))) short bfrag_t;   // 8 x bf16 (4 VGPRs)
typedef __attribute__((ext_vector_type(4))) float f4_t;
typedef __attribute__((ext_vector_type(2))) float f2_t;

#define LOG_2PI   1.8378770664093453f
#define TWO_LOG2  1.3862943611198906f
#define T_TILES   8            // 16-point tiles per wave
#define BLOCK     256          // 4 waves
#define PTS_BLK   512          // 4 waves * 8 tiles * 16 pts

struct SM {
  uint4    afr[2][2][8][64];   // 32KB [buf][mlp][frag=q*4+n][lane] pre-swizzled bf16 W2 A-frags
  float4   zst[PTS_BLK];       // 8KB  per-point flow state (z0, z1, ldet, pad)
  float    c1[6][2][64];       // 3KB  w1[j][jm]
  float    b1[6][2][64];       // 3KB  b1[j]
  float2   btw[PTS_BLK];       // 4KB  (base_term, weight)
  unsigned wb[6][2][64];       // 3KB  hi=bf16(w3[jo][h]) lo=bf16(b2[h])
  float    wsum[4];
};

__device__ __forceinline__ unsigned pkbf(float lo, float hi) {
  unsigned r;
  asm("v_cvt_pk_bf16_f32 %0, %1, %2" : "=v"(r) : "v"(lo), "v"(hi));
  return r;
}
__device__ __forceinline__ f2_t pk_fma(f2_t a, f2_t b, f2_t c) {
  f2_t d;
  asm("v_pk_fma_f32 %0, %1, %2, %3" : "=v"(d) : "v"(a), "v"(b), "v"(c));
  return d;
}
// leaky-relu on 2 lanes: packed mul (1 inst) + 2 scalar max (no v_pk_max_f32 on gfx950)
__device__ __forceinline__ f2_t pk_leaky(f2_t h, f2_t k01) {
  f2_t t, r;
  asm("v_pk_mul_f32 %0, %1, %2" : "=v"(t) : "v"(h), "v"(k01));
  r.x = fmaxf(h.x, t.x);
  r.y = fmaxf(h.y, t.y);
  return r;
}

// Stage one layer's W2 (both MLPs) into LDS as MFMA A-fragments (bf16).
// A-frag layout for mfma_f32_16x16x32_bf16: lane l holds A[16n + (l&15)][32q + 8*(l>>4) + e], e=0..7
__device__ __forceinline__ void stage_layer(SM* sm, const float* sW2, const float* tW2,
                                            int layer, int buf, int tid) {
  #pragma unroll
  for (int it = 0; it < 4; ++it) {
    int idx = tid + it * BLOCK;          // 0..1023
    int l = idx & 63, f = (idx >> 6) & 7, m = (idx >> 9) & 1;
    int n = f & 3, q = f >> 2;
    int row = 16 * n + (l & 15), kb = 32 * q + 8 * (l >> 4);
    const float* src = (m ? tW2 : sW2) + layer * 4096 + row * 64 + kb;
    float4 a = *(const float4*)src;
    float4 b = *(const float4*)(src + 4);
    uint4 v = make_uint4(pkbf(a.x, a.y), pkbf(a.z, a.w), pkbf(b.x, b.y), pkbf(b.z, b.w));
    sm->afr[buf][m][f][l] = v;
  }
}

__global__ __launch_bounds__(BLOCK)
__attribute__((amdgpu_waves_per_eu(2, 2)))
void ihll_kernel(
    const float* __restrict__ pred, const float* __restrict__ targ, const float* __restrict__ twp,
    const float* __restrict__ sW1, const float* __restrict__ sB1, const float* __restrict__ sW2,
    const float* __restrict__ sB2, const float* __restrict__ sW3, const float* __restrict__ sB3,
    const float* __restrict__ tW1, const float* __restrict__ tB1, const float* __restrict__ tW2,
    const float* __restrict__ tB2, const float* __restrict__ tW3, const float* __restrict__ tB3,
    float* __restrict__ out, int M) {
  __shared__ SM sm;
  const int tid  = threadIdx.x;
  const int lane = tid & 63, wave = tid >> 6;
  const int pr   = lane & 15, g = lane >> 4;
  const int pbase = blockIdx.x * PTS_BLK;
  const f2_t k01 = {0.01f, 0.01f};

  // ---- stage per-layer small tables (all 6 layers, once) ----
  for (int idx = tid; idx < 768; idx += BLOCK) {
    int i = idx >> 7, r = idx & 127, m = r >> 6, j = r & 63;
    int jo = i & 1, jm = jo ^ 1;                    // MASK[i]: i even -> m=[0,1] (jm=1, jo=0)
    const float* w1 = m ? tW1 : sW1;  const float* b1 = m ? tB1 : sB1;
    const float* w3 = m ? tW3 : sW3;  const float* b2 = m ? tB2 : sB2;
    sm.c1[i][m][j] = w1[i * 128 + j * 2 + jm];
    sm.b1[i][m][j] = b1[i * 64 + j];
    sm.wb[i][m][j] = pkbf(b2[i * 64 + j], w3[i * 128 + jo * 64 + j]);  // lo=b2, hi=w3
  }
  // ---- stage point data: flow state (z=error), base term, weight ----
  #pragma unroll
  for (int it = 0; it < 2; ++it) {
    int idx = tid + it * BLOCK;
    int P = pbase + idx;
    float4 zs = make_float4(0.f, 0.f, 0.f, 0.f);
    float2 bw = make_float2(0.f, 0.f);
    if (P < M) {
      float4 p4 = ((const float4*)pred)[P];
      float2 t2 = ((const float2*)targ)[P];
      float w   = twp[P];
      float s0 = sqrtf(fabsf(p4.z)), s1 = sqrtf(fabsf(p4.w));
      float e0 = (p4.x - t2.x) / (s0 + 1e-9f);
      float e1 = (p4.y - t2.y) / (s1 + 1e-9f);
      float bs = 2.f * (logf(s0) + logf(s1)) + TWO_LOG2 + fabsf(e0) + fabsf(e1);
      zs = make_float4(e0, e1, 0.f, 0.f);
      bw = make_float2(bs, w);
    }
    sm.zst[idx] = zs;
    sm.btw[idx] = bw;
  }
  stage_layer(&sm, sW2, tW2, 5, 0, tid);   // first layer processed is i=5
  __syncthreads();

  const int wbase = wave * (T_TILES * 16);

  // ---- layer loop: i = 5..0 ----
  #pragma unroll 1
  for (int li = 0; li < 6; ++li) {
    const int i = 5 - li;
    const int cur = li & 1;
    const int jo = i & 1;             // component written this layer
    const bool upd0 = (jo == 0);      // jo==0: input comp is z1, output z0

    // ---- per-layer constants into registers (resident; ~192 VGPR) ----
    uint4 af[2][8];
    #pragma unroll
    for (int m = 0; m < 2; ++m)
      #pragma unroll
      for (int f = 0; f < 8; ++f)
        af[m][f] = sm.afr[cur][m][f][lane];

    f2_t c1p[2][8], b1p[2][8];        // paired for v_pk_fma
    #pragma unroll
    for (int m = 0; m < 2; ++m)
      #pragma unroll
      for (int q = 0; q < 2; ++q)
        #pragma unroll
        for (int e2 = 0; e2 < 4; ++e2) {
          int j = q * 32 + 8 * g + 2 * e2;
          c1p[m][q * 4 + e2] = *(const f2_t*)&sm.c1[i][m][j];
          b1p[m][q * 4 + e2] = *(const f2_t*)&sm.b1[i][m][j];
        }
    f4_t b2v[2][4];                   // MFMA C-init (b2 per acc row)
    f2_t w3p[2][8];                   // paired w3 for the L3 dot
    #pragma unroll
    for (int m = 0; m < 2; ++m)
      #pragma unroll
      for (int n = 0; n < 4; ++n) {
        uint4 v = *(const uint4*)&sm.wb[i][m][n * 16 + 4 * g];
        b2v[m][n][0] = __uint_as_float(v.x << 16);
        b2v[m][n][1] = __uint_as_float(v.y << 16);
        b2v[m][n][2] = __uint_as_float(v.z << 16);
        b2v[m][n][3] = __uint_as_float(v.w << 16);
        w3p[m][2 * n]     = (f2_t){__uint_as_float(v.x & 0xffff0000u),
                                   __uint_as_float(v.y & 0xffff0000u)};
        w3p[m][2 * n + 1] = (f2_t){__uint_as_float(v.z & 0xffff0000u),
                                   __uint_as_float(v.w & 0xffff0000u)};
      }
    const float b3s = sB3[i * 2 + jo];
    const float b3t = tB3[i * 2 + jo];

    if (li < 5) stage_layer(&sm, sW2, tW2, i - 1, cur ^ 1, tid);  // prefetch next layer

    #pragma unroll 1
    for (int t = 0; t < T_TILES; ++t) {
      const int widx = wbase + t * 16 + pr;
      float4 zv = sm.zst[widx];                 // (z0, z1, ldet, -)
      const float zin = upd0 ? zv.y : zv.x;     // masked-in component z[jm]
      const f2_t zin2 = {zin, zin};
      float pre[2];
      #pragma unroll
      for (int m = 0; m < 2; ++m) {
        f4_t acc[4];
        #pragma unroll
        for (int q = 0; q < 2; ++q) {
          // layer 1: h1 = leaky(w1[:,jm]*zin + b1), 8 k-slots -> bf16 B-frag
          unsigned bb[4];
          #pragma unroll
          for (int e2 = 0; e2 < 4; ++e2) {
            f2_t h = pk_fma(c1p[m][q * 4 + e2], zin2, b1p[m][q * 4 + e2]);
            h = pk_leaky(h, k01);
            bb[e2] = pkbf(h.x, h.y);
          }
          bfrag_t B = __builtin_bit_cast(bfrag_t, make_uint4(bb[0], bb[1], bb[2], bb[3]));
          #pragma unroll
          for (int n = 0; n < 4; ++n) {
            f4_t c = (q == 0) ? b2v[m][n] : acc[n];   // fold b2 into first MFMA
            acc[n] = __builtin_amdgcn_mfma_f32_16x16x32_bf16(
                __builtin_bit_cast(bfrag_t, af[m][q * 4 + n]), B, c, 0, 0, 0);
          }
        }
        // layer 3: leaky(h2) . w3  via packed ops, reduce over the 4 lane-groups
        f2_t pacc = {0.f, 0.f};
        #pragma unroll
        for (int n = 0; n < 4; ++n) {
          f2_t lo = __builtin_shufflevector(acc[n], acc[n], 0, 1);
          f2_t hi = __builtin_shufflevector(acc[n], acc[n], 2, 3);
          lo = pk_leaky(lo, k01);
          pacc = pk_fma(lo, w3p[m][2 * n], pacc);
          hi = pk_leaky(hi, k01);
          pacc = pk_fma(hi, w3p[m][2 * n + 1], pacc);
        }
        float part = pacc.x + pacc.y;
        part += __shfl_xor(part, 16);
        part += __shfl_xor(part, 32);
        pre[m] = part;
      }
      // coupling update (identical across the 4 lane-groups)
      float esv = __expf(2.f * (pre[0] + b3s));
      float sv  = 1.f - 2.f / (esv + 1.f);          // tanh
      float tv  = pre[1] + b3t;
      float zo  = upd0 ? zv.x : zv.y;
      float zn  = (zo - tv) * __expf(-sv);
      if (upd0) zv.x = zn; else zv.y = zn;
      zv.z -= sv;
      if (g == 0) sm.zst[widx] = zv;
    }
    __syncthreads();
  }

  // ---- epilogue: prior + logdet -> loss contribution; reduce ----
  float csum = 0.f;
  #pragma unroll 1
  for (int t = 0; t < T_TILES; ++t) {
    const int widx = wbase + t * 16 + pr;
    float4 zv = sm.zst[widx];
    float2 bw = sm.btw[widx];
    float prior = -0.5f * (zv.x * zv.x + zv.y * zv.y) - LOG_2PI;
    float lphi  = prior + zv.z;
    csum += (bw.x - 2.f * lphi) * bw.y;
  }
  #pragma unroll
  for (int off = 1; off <= 32; off <<= 1)
    csum += __shfl_xor(csum, off);
  if (lane == 0) sm.wsum[wave] = csum;
  __syncthreads();
  if (tid == 0) {
    float tot = sm.wsum[0] + sm.wsum[1] + sm.wsum[2] + sm.wsum[3];
    // /4 for the 4x group replication, /8192 = /pred.shape[0]
    atomicAdd(out, tot * (1.0f / 32768.0f));
  }
}

extern "C" void kernel_launch(void* const* d_in, const int* in_sizes, int n_in,
                              void* d_out, int out_size, void* d_ws, size_t ws_size,
                              hipStream_t stream) {
  const float* pred = (const float*)d_in[0];
  const float* targ = (const float*)d_in[1];
  const float* twp  = (const float*)d_in[2];
  const float* sW1 = (const float*)d_in[3];  const float* sB1 = (const float*)d_in[4];
  const float* sW2 = (const float*)d_in[5];  const float* sB2 = (const float*)d_in[6];
  const float* sW3 = (const float*)d_in[7];  const float* sB3 = (const float*)d_in[8];
  const float* tW1 = (const float*)d_in[9];  const float* tB1 = (const float*)d_in[10];
  const float* tW2 = (const float*)d_in[11]; const float* tB2 = (const float*)d_in[12];
  const float* tW3 = (const float*)d_in[13]; const float* tB3 = (const float*)d_in[14];

  const int M = in_sizes[2];               // N*K points
  const int blocks = (M + PTS_BLK - 1) / PTS_BLK;

  hipMemsetAsync(d_out, 0, sizeof(float), stream);
  hipLaunchKernelGGL(ihll_kernel, dim3(blocks), dim3(BLOCK), 0, stream,
                     pred, targ, twp, sW1, sB1, sW2, sB2, sW3, sB3,
                     tW1, tB1, tW2, tB2, tW3, tB3, (float*)d_out, M);
}